// Round 1
// baseline (2803.997 us; speedup 1.0000x reference)
//
#include <hip/hip_runtime.h>
#include <math.h>

typedef unsigned short u16;
typedef unsigned int u32;

using bf16x8 = __attribute__((ext_vector_type(8))) __bf16;
using f32x4  = __attribute__((ext_vector_type(4))) float;

#define SEQ 3072
#define HID 1280
#define NHEADS 16
#define HDIM 80
#define INTER 4608

__device__ __forceinline__ u16 f2bf(float f) {
    union { float f; u32 u; } v; v.f = f;
    u32 u = v.u;
    u32 r = u + 0x7fffu + ((u >> 16) & 1u);   // round-to-nearest-even
    return (u16)(r >> 16);
}

__device__ __forceinline__ void gld16(const void* g, void* l) {
    __builtin_amdgcn_global_load_lds((const __attribute__((address_space(1))) void*)g,
                                     (__attribute__((address_space(3))) void*)l,
                                     16, 0, 0);
}

// ---------------- transpose + bf16 pack:  W (L,K,N) f32  ->  Wt (L,N,K) bf16
__global__ __launch_bounds__(256) void transpose_pack(const float* __restrict__ src,
                                                      u16* __restrict__ dst, int K, int N) {
    __shared__ float tile[32][33];
    int l = blockIdx.z;
    const float* s = src + (size_t)l * K * N;
    u16* d = dst + (size_t)l * N * K;
    int n0 = blockIdx.x * 32, k0 = blockIdx.y * 32;
    int tx = threadIdx.x & 31, ty = threadIdx.x >> 5;
#pragma unroll
    for (int i = 0; i < 4; i++) {
        int k = ty + i * 8;
        tile[k][tx] = s[(size_t)(k0 + k) * N + n0 + tx];
    }
    __syncthreads();
#pragma unroll
    for (int i = 0; i < 4; i++) {
        int n = ty + i * 8;
        d[(size_t)(n0 + n) * K + k0 + tx] = f2bf(tile[tx][n]);
    }
}

// ---------------- layernorm f32 -> bf16 (one row per block)
__global__ __launch_bounds__(256) void ln_kernel(const float* __restrict__ x,
                                                 const float* __restrict__ w,
                                                 const float* __restrict__ b,
                                                 u16* __restrict__ out) {
    int row = blockIdx.x;
    const float* xr = x + (size_t)row * HID;
    float v[5]; float s = 0.f, s2 = 0.f;
#pragma unroll
    for (int i = 0; i < 5; i++) { float t = xr[threadIdx.x + i * 256]; v[i] = t; s += t; s2 += t * t; }
#pragma unroll
    for (int off = 32; off > 0; off >>= 1) { s += __shfl_down(s, off); s2 += __shfl_down(s2, off); }
    __shared__ float red[8];
    int wv = threadIdx.x >> 6;
    if ((threadIdx.x & 63) == 0) { red[wv] = s; red[wv + 4] = s2; }
    __syncthreads();
    s  = red[0] + red[1] + red[2] + red[3];
    s2 = red[4] + red[5] + red[6] + red[7];
    float mu  = s * (1.f / HID);
    float var = s2 * (1.f / HID) - mu * mu;
    float rstd = rsqrtf(var + 1e-6f);
#pragma unroll
    for (int i = 0; i < 5; i++) {
        int col = threadIdx.x + i * 256;
        out[(size_t)row * HID + col] = f2bf((v[i] - mu) * rstd * w[col] + b[col]);
    }
}

// ---------------- rotary in-place on fp32 qkv buffer (S,3,16,80)
__global__ __launch_bounds__(256) void rotary_kernel(float* __restrict__ qkv,
                                                     const float* __restrict__ rot) {
    int s = blockIdx.x;
    __shared__ float cs[40], sn[40];
    if (threadIdx.x < 40) {
        float a = rot[(size_t)s * 40 + threadIdx.x];
        cs[threadIdx.x] = cosf(a); sn[threadIdx.x] = sinf(a);
    }
    __syncthreads();
    for (int idx = threadIdx.x; idx < 1280; idx += 256) {
        int qk  = idx / 640;
        int rem = idx - qk * 640;
        int hh  = rem / 40;
        int d   = rem - hh * 40;
        float* base = qkv + (size_t)s * 3840 + qk * 1280 + hh * 80;
        float x1 = base[d], x2 = base[d + 40];
        float c = cs[d], si = sn[d];
        base[d]      = x1 * c - x2 * si;
        base[d + 40] = x2 * c + x1 * si;
    }
}

// ---------------- bf16 MFMA GEMM: out(M,N) f32 = A(M,K)bf16 * Wt(N,K)bf16^T + bias (+res)
__global__ __launch_bounds__(256) void gemm_bf16(const u16* __restrict__ A,
                                                 const u16* __restrict__ Wt,
                                                 const float* __restrict__ bias,
                                                 const float* __restrict__ res,
                                                 float* __restrict__ out,
                                                 int M, int N, int K) {
    __shared__ u16 As[4096];   // 128 rows x 32 k, 16B-chunk swizzled
    __shared__ u16 Bs[4096];
    int tid = threadIdx.x;
    int lane = tid & 63, wave = tid >> 6;
    int quad = lane >> 4, r15 = lane & 15;
    int wm = wave >> 1, wn = wave & 1;
    int mBase = blockIdx.y * 128, nBase = blockIdx.x * 128;

    // staging: slot s (0..511) holds chunk (m=s>>2, q=(s&3)^((m>>1)&3)); wave covers 128 slots
    int sA0 = wave * 128 + lane, sA1 = sA0 + 64;
    int mA0 = sA0 >> 2, qA0 = (sA0 & 3) ^ ((mA0 >> 1) & 3);
    int mA1 = sA1 >> 2, qA1 = (sA1 & 3) ^ ((mA1 >> 1) & 3);
    const u16* gA0 = A + (size_t)(mBase + mA0) * K + qA0 * 8;
    const u16* gA1 = A + (size_t)(mBase + mA1) * K + qA1 * 8;
    const u16* gB0 = Wt + (size_t)(nBase + mA0) * K + qA0 * 8;
    const u16* gB1 = Wt + (size_t)(nBase + mA1) * K + qA1 * 8;
    u16* ldsA0 = &As[(wave * 128) * 8];
    u16* ldsA1 = &As[(wave * 128 + 64) * 8];
    u16* ldsB0 = &Bs[(wave * 128) * 8];
    u16* ldsB1 = &Bs[(wave * 128 + 64) * 8];

    int aOff[4], bOff[4];
#pragma unroll
    for (int i = 0; i < 4; i++) {
        int m = wm * 64 + i * 16 + r15;
        aOff[i] = (m * 4 + (quad ^ ((m >> 1) & 3))) * 8;
        int n = wn * 64 + i * 16 + r15;
        bOff[i] = (n * 4 + (quad ^ ((n >> 1) & 3))) * 8;
    }

    f32x4 acc[4][4] = {};
    int nK = K >> 5;
    for (int kt = 0; kt < nK; kt++) {
        int k0 = kt * 32;
        gld16(gA0 + k0, ldsA0);
        gld16(gA1 + k0, ldsA1);
        gld16(gB0 + k0, ldsB0);
        gld16(gB1 + k0, ldsB1);
        __syncthreads();
        bf16x8 af[4], bfr[4];
#pragma unroll
        for (int i = 0; i < 4; i++) {
            af[i]  = *(const bf16x8*)&As[aOff[i]];
            bfr[i] = *(const bf16x8*)&Bs[bOff[i]];
        }
#pragma unroll
        for (int mi = 0; mi < 4; mi++)
#pragma unroll
            for (int ni = 0; ni < 4; ni++)
                acc[mi][ni] = __builtin_amdgcn_mfma_f32_16x16x32_bf16(af[mi], bfr[ni], acc[mi][ni], 0, 0, 0);
        __syncthreads();
    }

#pragma unroll
    for (int ni = 0; ni < 4; ni++) {
        int col = nBase + wn * 64 + ni * 16 + r15;
        float bv = bias[col];
#pragma unroll
        for (int mi = 0; mi < 4; mi++) {
#pragma unroll
            for (int j = 0; j < 4; j++) {
                int row = mBase + wm * 64 + mi * 16 + quad * 4 + j;
                float o = acc[mi][ni][j] + bv;
                if (res) o += res[(size_t)row * N + col];
                out[(size_t)row * N + col] = o;
            }
        }
    }
}

// ---------------- flash attention with sinks (MFMA), one block per (q-tile of 64, head)
__global__ __launch_bounds__(256) void attn_kernel(const float* __restrict__ qkv,
                                                   const float* __restrict__ s_aux,
                                                   u16* __restrict__ out, int windowed) {
    __shared__ u16 q_lds[64 * 104];   // [row][dim<96 pad0, stride 104]
    __shared__ u16 k_lds[64 * 104];
    __shared__ u16 vt_lds[80 * 72];   // [dim][key, stride 72]
    __shared__ u16 p_lds[4 * 16 * 72];// [wave][row][key, stride 72]

    int qt = blockIdx.x, h = blockIdx.y;
    int tid = threadIdx.x, lane = tid & 63, wave = tid >> 6;
    int quad = lane >> 4, r15 = lane & 15;
    const float scale = 0.111803398874989485f;  // 1/sqrt(80)

    const float* qbase = qkv + (size_t)(qt * 64) * 3840 + h * 80;
    for (int idx = tid; idx < 64 * 96; idx += 256) {
        int row = idx / 96, d = idx - row * 96;
        float v = (d < 80) ? qbase[(size_t)row * 3840 + d] : 0.f;
        q_lds[row * 104 + d] = f2bf(v);
    }
    __syncthreads();
    bf16x8 aq[3];
#pragma unroll
    for (int ks = 0; ks < 3; ks++)
        aq[ks] = *(const bf16x8*)&q_lds[(wave * 16 + r15) * 104 + ks * 32 + quad * 8];

    float sink = s_aux[h];
    float m_i[4], l_i[4];
#pragma unroll
    for (int j = 0; j < 4; j++) { m_i[j] = sink; l_i[j] = 1.f; }
    f32x4 ov[5] = {};

    int nT = windowed ? 1 : (SEQ / 64);
    int tBase = windowed ? qt : 0;
    for (int t = 0; t < nT; t++) {
        int key0 = (tBase + t) * 64;
        const float* kb = qkv + (size_t)key0 * 3840 + 1280 + h * 80;
        const float* vb = qkv + (size_t)key0 * 3840 + 2560 + h * 80;
        __syncthreads();   // prev iter's LDS consumers done
        for (int idx = tid; idx < 64 * 96; idx += 256) {
            int row = idx / 96, d = idx - row * 96;
            float v = (d < 80) ? kb[(size_t)row * 3840 + d] : 0.f;
            k_lds[row * 104 + d] = f2bf(v);
        }
        for (int idx = tid; idx < 64 * 80; idx += 256) {
            int row = idx / 80, d = idx - row * 80;
            vt_lds[d * 72 + row] = f2bf(vb[(size_t)row * 3840 + d]);
        }
        __syncthreads();

        f32x4 sc[4];
#pragma unroll
        for (int nt = 0; nt < 4; nt++) {
            f32x4 z = {};
#pragma unroll
            for (int ks = 0; ks < 3; ks++) {
                bf16x8 bk = *(const bf16x8*)&k_lds[(nt * 16 + r15) * 104 + ks * 32 + quad * 8];
                z = __builtin_amdgcn_mfma_f32_16x16x32_bf16(aq[ks], bk, z, 0, 0, 0);
            }
            sc[nt] = z * scale;
        }
        float mx[4], ls[4], p_[4][4];
#pragma unroll
        for (int j = 0; j < 4; j++)
            mx[j] = fmaxf(fmaxf(sc[0][j], sc[1][j]), fmaxf(sc[2][j], sc[3][j]));
#pragma unroll
        for (int off = 1; off < 16; off <<= 1)
#pragma unroll
            for (int j = 0; j < 4; j++)
                mx[j] = fmaxf(mx[j], __shfl_xor(mx[j], off, 16));
        float alpha[4];
#pragma unroll
        for (int j = 0; j < 4; j++) {
            float mn = fmaxf(m_i[j], mx[j]);
            alpha[j] = __expf(m_i[j] - mn);
            m_i[j] = mn;
            ls[j] = 0.f;
        }
#pragma unroll
        for (int nt = 0; nt < 4; nt++)
#pragma unroll
            for (int j = 0; j < 4; j++) {
                float e = __expf(sc[nt][j] - m_i[j]);
                p_[nt][j] = e; ls[j] += e;
            }
#pragma unroll
        for (int off = 1; off < 16; off <<= 1)
#pragma unroll
            for (int j = 0; j < 4; j++)
                ls[j] += __shfl_xor(ls[j], off, 16);
#pragma unroll
        for (int j = 0; j < 4; j++) l_i[j] = l_i[j] * alpha[j] + ls[j];
#pragma unroll
        for (int t5 = 0; t5 < 5; t5++)
#pragma unroll
            for (int j = 0; j < 4; j++) ov[t5][j] *= alpha[j];
        // P: C-layout (row=quad*4+j, col=nt*16+r15) -> LDS [row][key]
#pragma unroll
        for (int nt = 0; nt < 4; nt++)
#pragma unroll
            for (int j = 0; j < 4; j++)
                p_lds[(wave * 16 + quad * 4 + j) * 72 + nt * 16 + r15] = f2bf(p_[nt][j]);
        __syncthreads();
        bf16x8 ap[2];
#pragma unroll
        for (int ks = 0; ks < 2; ks++)
            ap[ks] = *(const bf16x8*)&p_lds[(wave * 16 + r15) * 72 + ks * 32 + quad * 8];
#pragma unroll
        for (int t5 = 0; t5 < 5; t5++) {
#pragma unroll
            for (int ks = 0; ks < 2; ks++) {
                bf16x8 bv = *(const bf16x8*)&vt_lds[(t5 * 16 + r15) * 72 + ks * 32 + quad * 8];
                ov[t5] = __builtin_amdgcn_mfma_f32_16x16x32_bf16(ap[ks], bv, ov[t5], 0, 0, 0);
            }
        }
    }
#pragma unroll
    for (int t5 = 0; t5 < 5; t5++)
#pragma unroll
        for (int j = 0; j < 4; j++) {
            int row = qt * 64 + wave * 16 + quad * 4 + j;
            int d = t5 * 16 + r15;
            out[(size_t)row * HID + h * 80 + d] = f2bf(ov[t5][j] / l_i[j]);
        }
}

// ---------------- silu(g)*u -> bf16
__global__ __launch_bounds__(256) void silu_mul_kernel(const float* __restrict__ g,
                                                       const float* __restrict__ u,
                                                       u16* __restrict__ out) {
    size_t i = (size_t)blockIdx.x * 256 + threadIdx.x;
    float4 gv = ((const float4*)g)[i];
    float4 uv = ((const float4*)u)[i];
    float r0 = gv.x / (1.f + __expf(-gv.x)) * uv.x;
    float r1 = gv.y / (1.f + __expf(-gv.y)) * uv.y;
    float r2 = gv.z / (1.f + __expf(-gv.z)) * uv.z;
    float r3 = gv.w / (1.f + __expf(-gv.w)) * uv.w;
    ushort4 o; o.x = f2bf(r0); o.y = f2bf(r1); o.z = f2bf(r2); o.w = f2bf(r3);
    ((ushort4*)out)[i] = o;
}

__global__ __launch_bounds__(256) void copy4_kernel(const float4* __restrict__ src,
                                                    float4* __restrict__ dst) {
    size_t i = (size_t)blockIdx.x * 256 + threadIdx.x;
    dst[i] = src[i];
}

extern "C" void kernel_launch(void* const* d_in, const int* in_sizes, int n_in,
                              void* d_out, int out_size, void* d_ws, size_t ws_size,
                              hipStream_t stream) {
    const float* x      = (const float*)d_in[0];
    const float* rot    = (const float*)d_in[1];
    const float* s_aux  = (const float*)d_in[2];
    const float* ln1_w  = (const float*)d_in[3];
    const float* ln1_b  = (const float*)d_in[4];
    const float* qkv_w  = (const float*)d_in[5];
    const float* qkv_b  = (const float*)d_in[6];
    const float* proj_w = (const float*)d_in[7];
    const float* proj_b = (const float*)d_in[8];
    const float* ln2_w  = (const float*)d_in[9];
    const float* ln2_b  = (const float*)d_in[10];
    const float* gate_w = (const float*)d_in[11];
    const float* gate_b = (const float*)d_in[12];
    const float* up_w   = (const float*)d_in[13];
    const float* up_b   = (const float*)d_in[14];
    const float* down_w = (const float*)d_in[15];
    const float* down_b = (const float*)d_in[16];

    char* ws = (char*)d_ws;
    size_t off = 0;
    auto alloc = [&](size_t n) -> char* {
        char* p = ws + off; off += (n + 255) & ~(size_t)255; return p;
    };
    u16* wt_qkv  = (u16*)alloc((size_t)4 * 3840 * 1280 * 2);
    u16* wt_proj = (u16*)alloc((size_t)4 * 1280 * 1280 * 2);
    u16* wt_gate = (u16*)alloc((size_t)4 * 4608 * 1280 * 2);
    u16* wt_up   = (u16*)alloc((size_t)4 * 4608 * 1280 * 2);
    u16* wt_down = (u16*)alloc((size_t)4 * 1280 * 4608 * 2);
    float* h     = (float*)alloc((size_t)3072 * 1280 * 4);
    u16*  xn     = (u16*)alloc((size_t)3072 * 1280 * 2);
    float* gbuf  = (float*)alloc((size_t)3072 * 4608 * 4);
    float* qkvb  = gbuf;  // alias: qkv buffer (47.2MB) dead before gate GEMM writes gbuf (56.6MB)
    u16*  attnb  = (u16*)alloc((size_t)3072 * 1280 * 2);
    float* ubuf  = (float*)alloc((size_t)3072 * 4608 * 4);
    u16*  mbuf   = (u16*)alloc((size_t)3072 * 4608 * 2);

    // weight packs (per call; harness re-poisons ws each launch)
    transpose_pack<<<dim3(120, 40, 4), 256, 0, stream>>>(qkv_w,  wt_qkv,  1280, 3840);
    transpose_pack<<<dim3(40,  40, 4), 256, 0, stream>>>(proj_w, wt_proj, 1280, 1280);
    transpose_pack<<<dim3(144, 40, 4), 256, 0, stream>>>(gate_w, wt_gate, 1280, 4608);
    transpose_pack<<<dim3(144, 40, 4), 256, 0, stream>>>(up_w,   wt_up,   1280, 4608);
    transpose_pack<<<dim3(40, 144, 4), 256, 0, stream>>>(down_w, wt_down, 4608, 1280);

    copy4_kernel<<<3840, 256, 0, stream>>>((const float4*)x, (float4*)h);

    for (int l = 0; l < 4; l++) {
        ln_kernel<<<3072, 256, 0, stream>>>(h, ln1_w + l * 1280, ln1_b + l * 1280, xn);
        gemm_bf16<<<dim3(30, 24), 256, 0, stream>>>(xn, wt_qkv + (size_t)l * 3840 * 1280,
                                                    qkv_b + l * 3840, nullptr, qkvb, 3072, 3840, 1280);
        rotary_kernel<<<3072, 256, 0, stream>>>(qkvb, rot);
        attn_kernel<<<dim3(48, 16), 256, 0, stream>>>(qkvb, s_aux, attnb, (l == 3) ? 0 : 1);
        gemm_bf16<<<dim3(10, 24), 256, 0, stream>>>(attnb, wt_proj + (size_t)l * 1280 * 1280,
                                                    proj_b + l * 1280, h, h, 3072, 1280, 1280);
        ln_kernel<<<3072, 256, 0, stream>>>(h, ln2_w + l * 1280, ln2_b + l * 1280, xn);
        gemm_bf16<<<dim3(36, 24), 256, 0, stream>>>(xn, wt_gate + (size_t)l * 4608 * 1280,
                                                    gate_b + l * 4608, nullptr, gbuf, 3072, 4608, 1280);
        gemm_bf16<<<dim3(36, 24), 256, 0, stream>>>(xn, wt_up + (size_t)l * 4608 * 1280,
                                                    up_b + l * 4608, nullptr, ubuf, 3072, 4608, 1280);
        silu_mul_kernel<<<13824, 256, 0, stream>>>(gbuf, ubuf, mbuf);
        float* outp = (l == 3) ? (float*)d_out : h;
        gemm_bf16<<<dim3(10, 24), 256, 0, stream>>>(mbuf, wt_down + (size_t)l * 4608 * 1280,
                                                    down_b + l * 1280, h, outp, 3072, 1280, 4608);
    }
}

// Round 2
// 2297.662 us; speedup vs baseline: 1.2204x; 1.2204x over previous
//
#include <hip/hip_runtime.h>
#include <math.h>

typedef unsigned short u16;
typedef unsigned int u32;

using bf16x8 = __attribute__((ext_vector_type(8))) __bf16;
using f32x4  = __attribute__((ext_vector_type(4))) float;

#define SEQ 3072
#define HID 1280
#define NHEADS 16
#define HDIM 80
#define INTER 4608

#define LOG2E 1.44269504088896f
#define M2C   11.5415603f   /* 8 * log2(e) */

__device__ __forceinline__ u16 f2bf(float f) {
    union { float f; u32 u; } v; v.f = f;
    u32 u = v.u;
    u32 r = u + 0x7fffu + ((u >> 16) & 1u);   // round-to-nearest-even
    return (u16)(r >> 16);
}

__device__ __forceinline__ void gld16(const void* g, void* l) {
    __builtin_amdgcn_global_load_lds((const __attribute__((address_space(1))) void*)g,
                                     (__attribute__((address_space(3))) void*)l,
                                     16, 0, 0);
}

// ---------------- transpose + bf16 pack:  W (L,K,N) f32  ->  Wt (L,N,K) bf16
__global__ __launch_bounds__(256) void transpose_pack(const float* __restrict__ src,
                                                      u16* __restrict__ dst, int K, int N) {
    __shared__ float tile[32][33];
    int l = blockIdx.z;
    const float* s = src + (size_t)l * K * N;
    u16* d = dst + (size_t)l * N * K;
    int n0 = blockIdx.x * 32, k0 = blockIdx.y * 32;
    int tx = threadIdx.x & 31, ty = threadIdx.x >> 5;
#pragma unroll
    for (int i = 0; i < 4; i++) {
        int k = ty + i * 8;
        tile[k][tx] = s[(size_t)(k0 + k) * N + n0 + tx];
    }
    __syncthreads();
#pragma unroll
    for (int i = 0; i < 4; i++) {
        int n = ty + i * 8;
        d[(size_t)(n0 + n) * K + k0 + tx] = f2bf(tile[tx][n]);
    }
}

// ---------------- layernorm f32 -> bf16 (one row per block)
__global__ __launch_bounds__(256) void ln_kernel(const float* __restrict__ x,
                                                 const float* __restrict__ w,
                                                 const float* __restrict__ b,
                                                 u16* __restrict__ out) {
    int row = blockIdx.x;
    const float* xr = x + (size_t)row * HID;
    float v[5]; float s = 0.f, s2 = 0.f;
#pragma unroll
    for (int i = 0; i < 5; i++) { float t = xr[threadIdx.x + i * 256]; v[i] = t; s += t; s2 += t * t; }
#pragma unroll
    for (int off = 32; off > 0; off >>= 1) { s += __shfl_down(s, off); s2 += __shfl_down(s2, off); }
    __shared__ float red[8];
    int wv = threadIdx.x >> 6;
    if ((threadIdx.x & 63) == 0) { red[wv] = s; red[wv + 4] = s2; }
    __syncthreads();
    s  = red[0] + red[1] + red[2] + red[3];
    s2 = red[4] + red[5] + red[6] + red[7];
    float mu  = s * (1.f / HID);
    float var = s2 * (1.f / HID) - mu * mu;
    float rstd = rsqrtf(var + 1e-6f);
#pragma unroll
    for (int i = 0; i < 5; i++) {
        int col = threadIdx.x + i * 256;
        out[(size_t)row * HID + col] = f2bf((v[i] - mu) * rstd * w[col] + b[col]);
    }
}

// ---------------- qkv pack: fp32 qkv (S,3,16,80) -> rotary + bf16 attention layouts
// Qp/Kp: [h][s][128] (zero pad 80..127, Q pre-scaled by scale*log2e); Vt: [h][d][s]
__global__ __launch_bounds__(256) void qkv_pack(const float* __restrict__ qkv,
                                                const float* __restrict__ rot,
                                                u16* __restrict__ Qp, u16* __restrict__ Kp,
                                                u16* __restrict__ Vt) {
    const float QSC = 0.111803398874989485f * LOG2E;
    int s0 = blockIdx.x * 64, h = blockIdx.y;
    int tid = threadIdx.x;
    __shared__ u16 vlds[80 * 66];
    for (int idx = tid; idx < 64 * 40; idx += 256) {
        int r = idx / 40, d = idx - r * 40;
        const float* base = qkv + (size_t)(s0 + r) * 3840 + h * 80;
        float sn, cs;
        __sincosf(rot[(size_t)(s0 + r) * 40 + d], &sn, &cs);
        float q1 = base[d], q2 = base[d + 40];
        float k1 = base[1280 + d], k2 = base[1280 + d + 40];
        size_t ro = ((size_t)h * SEQ + s0 + r) * 128;
        Qp[ro + d]      = f2bf((q1 * cs - q2 * sn) * QSC);
        Qp[ro + d + 40] = f2bf((q2 * cs + q1 * sn) * QSC);
        Kp[ro + d]      = f2bf(k1 * cs - k2 * sn);
        Kp[ro + d + 40] = f2bf(k2 * cs + k1 * sn);
    }
    for (int idx = tid; idx < 64 * 48; idx += 256) {
        int r = idx / 48, d = 80 + (idx - r * 48);
        size_t ro = ((size_t)h * SEQ + s0 + r) * 128;
        Qp[ro + d] = 0; Kp[ro + d] = 0;
    }
    for (int idx = tid; idx < 64 * 80; idx += 256) {
        int r = idx / 80, d = idx - r * 80;
        vlds[d * 66 + r] = f2bf(qkv[(size_t)(s0 + r) * 3840 + 2560 + h * 80 + d]);
    }
    __syncthreads();
    for (int idx = tid; idx < 80 * 64; idx += 256) {
        int d = idx >> 6, ky = idx & 63;
        Vt[((size_t)h * 80 + d) * SEQ + s0 + ky] = vlds[d * 66 + ky];
    }
}

// ---------------- bf16 MFMA GEMM: out(M,N) f32 = A(M,K)bf16 * Wt(N,K)bf16^T + bias (+res)
__global__ __launch_bounds__(256) void gemm_bf16(const u16* __restrict__ A,
                                                 const u16* __restrict__ Wt,
                                                 const float* __restrict__ bias,
                                                 const float* __restrict__ res,
                                                 float* __restrict__ out,
                                                 int M, int N, int K) {
    __shared__ u16 As[4096];   // 128 rows x 32 k, 16B-chunk swizzled
    __shared__ u16 Bs[4096];
    int tid = threadIdx.x;
    int lane = tid & 63, wave = tid >> 6;
    int quad = lane >> 4, r15 = lane & 15;
    int wm = wave >> 1, wn = wave & 1;
    int mBase = blockIdx.y * 128, nBase = blockIdx.x * 128;

    int sA0 = wave * 128 + lane, sA1 = sA0 + 64;
    int mA0 = sA0 >> 2, qA0 = (sA0 & 3) ^ ((mA0 >> 1) & 3);
    int mA1 = sA1 >> 2, qA1 = (sA1 & 3) ^ ((mA1 >> 1) & 3);
    const u16* gA0 = A + (size_t)(mBase + mA0) * K + qA0 * 8;
    const u16* gA1 = A + (size_t)(mBase + mA1) * K + qA1 * 8;
    const u16* gB0 = Wt + (size_t)(nBase + mA0) * K + qA0 * 8;
    const u16* gB1 = Wt + (size_t)(nBase + mA1) * K + qA1 * 8;
    u16* ldsA0 = &As[(wave * 128) * 8];
    u16* ldsA1 = &As[(wave * 128 + 64) * 8];
    u16* ldsB0 = &Bs[(wave * 128) * 8];
    u16* ldsB1 = &Bs[(wave * 128 + 64) * 8];

    int aOff[4], bOff[4];
#pragma unroll
    for (int i = 0; i < 4; i++) {
        int m = wm * 64 + i * 16 + r15;
        aOff[i] = (m * 4 + (quad ^ ((m >> 1) & 3))) * 8;
        int n = wn * 64 + i * 16 + r15;
        bOff[i] = (n * 4 + (quad ^ ((n >> 1) & 3))) * 8;
    }

    f32x4 acc[4][4] = {};
    int nK = K >> 5;
    for (int kt = 0; kt < nK; kt++) {
        int k0 = kt * 32;
        gld16(gA0 + k0, ldsA0);
        gld16(gA1 + k0, ldsA1);
        gld16(gB0 + k0, ldsB0);
        gld16(gB1 + k0, ldsB1);
        __syncthreads();
        bf16x8 af[4], bfr[4];
#pragma unroll
        for (int i = 0; i < 4; i++) {
            af[i]  = *(const bf16x8*)&As[aOff[i]];
            bfr[i] = *(const bf16x8*)&Bs[bOff[i]];
        }
#pragma unroll
        for (int mi = 0; mi < 4; mi++)
#pragma unroll
            for (int ni = 0; ni < 4; ni++)
                acc[mi][ni] = __builtin_amdgcn_mfma_f32_16x16x32_bf16(af[mi], bfr[ni], acc[mi][ni], 0, 0, 0);
        __syncthreads();
    }

#pragma unroll
    for (int ni = 0; ni < 4; ni++) {
        int col = nBase + wn * 64 + ni * 16 + r15;
        float bv = bias[col];
#pragma unroll
        for (int mi = 0; mi < 4; mi++) {
#pragma unroll
            for (int j = 0; j < 4; j++) {
                int row = mBase + wm * 64 + mi * 16 + quad * 4 + j;
                float o = acc[mi][ni][j] + bv;
                if (res) o += res[(size_t)row * N + col];
                out[(size_t)row * N + col] = o;
            }
        }
    }
}

// ---------------- flash attention with sinks v2: prepacked bf16 in, gld16 staging,
// static-max softmax (exp2, deferred denominator). One block per (q-tile 64, head).
__global__ __launch_bounds__(256) void attn_kernel(const u16* __restrict__ Qp,
                                                   const u16* __restrict__ Kp,
                                                   const u16* __restrict__ Vt,
                                                   const float* __restrict__ s_aux,
                                                   u16* __restrict__ out, int windowed) {
    __shared__ u16 q_lds[8192];   // 64 rows x 16 chunks (swizzled)
    __shared__ u16 k_lds[8192];
    __shared__ u16 v_lds[5120];   // 80 rows x 8 chunks (swizzled)
    __shared__ u16 p_lds[64 * 72];

    int qt = blockIdx.x, h = blockIdx.y;
    int tid = threadIdx.x, lane = tid & 63, wave = tid >> 6;
    int quad = lane >> 4, r15 = lane & 15;

    const u16* Qh = Qp + (size_t)h * SEQ * 128;
    const u16* Kh = Kp + (size_t)h * SEQ * 128;
    const u16* Vh = Vt + (size_t)h * 80 * SEQ;

    {   // stage Q tile
        int q0 = qt * 64;
#pragma unroll
        for (int i = 0; i < 4; i++) {
            int slot = i * 256 + wave * 64 + lane;
            int row = slot >> 4, cs = slot & 15;
            int c = cs ^ (row & 7);
            gld16(Qh + (size_t)(q0 + row) * 128 + c * 8, &q_lds[(i * 256 + wave * 64) * 8]);
        }
    }
    __syncthreads();
    bf16x8 aq[3];
#pragma unroll
    for (int ks = 0; ks < 3; ks++) {
        int row = wave * 16 + r15;
        int c = ks * 4 + quad;
        aq[ks] = *(const bf16x8*)&q_lds[(row * 16 + (c ^ (row & 7))) * 8];
    }

    float l_j[4] = {0.f, 0.f, 0.f, 0.f};
    f32x4 ov[5] = {};

    int nT = windowed ? 1 : (SEQ / 64);
    int tBase = windowed ? qt : 0;
    for (int t = 0; t < nT; t++) {
        int key0 = (tBase + t) * 64;
        __syncthreads();   // prev iter's LDS consumers done
#pragma unroll
        for (int i = 0; i < 4; i++) {
            int slot = i * 256 + wave * 64 + lane;
            int row = slot >> 4, cs = slot & 15;
            int c = cs ^ (row & 7);
            gld16(Kh + (size_t)(key0 + row) * 128 + c * 8, &k_lds[(i * 256 + wave * 64) * 8]);
        }
#pragma unroll
        for (int i = 0; i < 2; i++) {
            int slot = i * 256 + wave * 64 + lane;
            int row = slot >> 3, cs = slot & 7;
            int c = cs ^ (row & 7);
            gld16(Vh + (size_t)row * SEQ + key0 + c * 8, &v_lds[(i * 256 + wave * 64) * 8]);
        }
        if (wave < 2) {
            int slot = 512 + wave * 64 + lane;
            int row = slot >> 3, cs = slot & 7;
            int c = cs ^ (row & 7);
            gld16(Vh + (size_t)row * SEQ + key0 + c * 8, &v_lds[(512 + wave * 64) * 8]);
        }
        __syncthreads();

        f32x4 sc[4];
#pragma unroll
        for (int nt = 0; nt < 4; nt++) {
            f32x4 z = {};
#pragma unroll
            for (int ks = 0; ks < 3; ks++) {
                int row = nt * 16 + r15;
                int c = ks * 4 + quad;
                bf16x8 bk = *(const bf16x8*)&k_lds[(row * 16 + (c ^ (row & 7))) * 8];
                z = __builtin_amdgcn_mfma_f32_16x16x32_bf16(aq[ks], bk, z, 0, 0, 0);
            }
            sc[nt] = z;
        }
        // static-max softmax: p = exp2(z - M2C); denominator deferred
#pragma unroll
        for (int nt = 0; nt < 4; nt++)
#pragma unroll
            for (int j = 0; j < 4; j++) {
                float p = __builtin_amdgcn_exp2f(sc[nt][j] - M2C);
                l_j[j] += p;
                p_lds[(wave * 16 + quad * 4 + j) * 72 + nt * 16 + r15] = f2bf(p);
            }
        // P round-trip is wave-local (rows wave*16..): wave-level wait suffices
        asm volatile("s_waitcnt lgkmcnt(0)" ::: "memory");
        bf16x8 ap[2];
#pragma unroll
        for (int ks = 0; ks < 2; ks++)
            ap[ks] = *(const bf16x8*)&p_lds[(wave * 16 + r15) * 72 + ks * 32 + quad * 8];
#pragma unroll
        for (int t5 = 0; t5 < 5; t5++)
#pragma unroll
            for (int ks = 0; ks < 2; ks++) {
                int d = t5 * 16 + r15;
                int c = ks * 4 + quad;
                bf16x8 bv = *(const bf16x8*)&v_lds[(d * 8 + (c ^ (d & 7))) * 8];
                ov[t5] = __builtin_amdgcn_mfma_f32_16x16x32_bf16(ap[ks], bv, ov[t5], 0, 0, 0);
            }
    }
    // row-sum reduce across the 16 lanes sharing a quad (cols r15)
#pragma unroll
    for (int off = 1; off < 16; off <<= 1)
#pragma unroll
        for (int j = 0; j < 4; j++)
            l_j[j] += __shfl_xor(l_j[j], off, 64);
    float sink = s_aux[h];
    float se = __builtin_amdgcn_exp2f(sink * LOG2E - M2C);
#pragma unroll
    for (int j = 0; j < 4; j++) l_j[j] = 1.f / (l_j[j] + se);
#pragma unroll
    for (int t5 = 0; t5 < 5; t5++)
#pragma unroll
        for (int j = 0; j < 4; j++) {
            int row = qt * 64 + wave * 16 + quad * 4 + j;
            int d = t5 * 16 + r15;
            out[(size_t)row * HID + h * 80 + d] = f2bf(ov[t5][j] * l_j[j]);
        }
}

// ---------------- silu(g)*u -> bf16
__global__ __launch_bounds__(256) void silu_mul_kernel(const float* __restrict__ g,
                                                       const float* __restrict__ u,
                                                       u16* __restrict__ out) {
    size_t i = (size_t)blockIdx.x * 256 + threadIdx.x;
    float4 gv = ((const float4*)g)[i];
    float4 uv = ((const float4*)u)[i];
    float r0 = gv.x / (1.f + __expf(-gv.x)) * uv.x;
    float r1 = gv.y / (1.f + __expf(-gv.y)) * uv.y;
    float r2 = gv.z / (1.f + __expf(-gv.z)) * uv.z;
    float r3 = gv.w / (1.f + __expf(-gv.w)) * uv.w;
    ushort4 o; o.x = f2bf(r0); o.y = f2bf(r1); o.z = f2bf(r2); o.w = f2bf(r3);
    ((ushort4*)out)[i] = o;
}

__global__ __launch_bounds__(256) void copy4_kernel(const float4* __restrict__ src,
                                                    float4* __restrict__ dst) {
    size_t i = (size_t)blockIdx.x * 256 + threadIdx.x;
    dst[i] = src[i];
}

extern "C" void kernel_launch(void* const* d_in, const int* in_sizes, int n_in,
                              void* d_out, int out_size, void* d_ws, size_t ws_size,
                              hipStream_t stream) {
    const float* x      = (const float*)d_in[0];
    const float* rot    = (const float*)d_in[1];
    const float* s_aux  = (const float*)d_in[2];
    const float* ln1_w  = (const float*)d_in[3];
    const float* ln1_b  = (const float*)d_in[4];
    const float* qkv_w  = (const float*)d_in[5];
    const float* qkv_b  = (const float*)d_in[6];
    const float* proj_w = (const float*)d_in[7];
    const float* proj_b = (const float*)d_in[8];
    const float* ln2_w  = (const float*)d_in[9];
    const float* ln2_b  = (const float*)d_in[10];
    const float* gate_w = (const float*)d_in[11];
    const float* gate_b = (const float*)d_in[12];
    const float* up_w   = (const float*)d_in[13];
    const float* up_b   = (const float*)d_in[14];
    const float* down_w = (const float*)d_in[15];
    const float* down_b = (const float*)d_in[16];

    char* ws = (char*)d_ws;
    size_t off = 0;
    auto alloc = [&](size_t n) -> char* {
        char* p = ws + off; off += (n + 255) & ~(size_t)255; return p;
    };
    u16* wt_qkv  = (u16*)alloc((size_t)4 * 3840 * 1280 * 2);
    u16* wt_proj = (u16*)alloc((size_t)4 * 1280 * 1280 * 2);
    u16* wt_gate = (u16*)alloc((size_t)4 * 4608 * 1280 * 2);
    u16* wt_up   = (u16*)alloc((size_t)4 * 4608 * 1280 * 2);
    u16* wt_down = (u16*)alloc((size_t)4 * 1280 * 4608 * 2);
    float* h     = (float*)alloc((size_t)3072 * 1280 * 4);
    u16*  xn     = (u16*)alloc((size_t)3072 * 1280 * 2);
    float* gbuf  = (float*)alloc((size_t)3072 * 4608 * 4);
    float* qkvb  = gbuf;  // alias: qkv buffer dead before gate GEMM writes gbuf
    u16*  attnb  = (u16*)alloc((size_t)3072 * 1280 * 2);
    float* ubuf  = (float*)alloc((size_t)3072 * 4608 * 4);
    u16*  mbuf   = (u16*)alloc((size_t)3072 * 4608 * 2);
    // attention packs alias ubuf (live pack->attn; ubuf live up-GEMM->silu; disjoint)
    u16* Qp  = (u16*)ubuf;                      // 16*3072*128
    u16* Kp  = Qp + (size_t)NHEADS * SEQ * 128; // 16*3072*128
    u16* Vtp = Kp + (size_t)NHEADS * SEQ * 128; // 16*80*3072

    transpose_pack<<<dim3(120, 40, 4), 256, 0, stream>>>(qkv_w,  wt_qkv,  1280, 3840);
    transpose_pack<<<dim3(40,  40, 4), 256, 0, stream>>>(proj_w, wt_proj, 1280, 1280);
    transpose_pack<<<dim3(144, 40, 4), 256, 0, stream>>>(gate_w, wt_gate, 1280, 4608);
    transpose_pack<<<dim3(144, 40, 4), 256, 0, stream>>>(up_w,   wt_up,   1280, 4608);
    transpose_pack<<<dim3(40, 144, 4), 256, 0, stream>>>(down_w, wt_down, 4608, 1280);

    copy4_kernel<<<3840, 256, 0, stream>>>((const float4*)x, (float4*)h);

    for (int l = 0; l < 4; l++) {
        ln_kernel<<<3072, 256, 0, stream>>>(h, ln1_w + l * 1280, ln1_b + l * 1280, xn);
        gemm_bf16<<<dim3(30, 24), 256, 0, stream>>>(xn, wt_qkv + (size_t)l * 3840 * 1280,
                                                    qkv_b + l * 3840, nullptr, qkvb, 3072, 3840, 1280);
        qkv_pack<<<dim3(48, 16), 256, 0, stream>>>(qkvb, rot, Qp, Kp, Vtp);
        attn_kernel<<<dim3(48, 16), 256, 0, stream>>>(Qp, Kp, Vtp, s_aux, attnb, (l == 3) ? 0 : 1);
        gemm_bf16<<<dim3(10, 24), 256, 0, stream>>>(attnb, wt_proj + (size_t)l * 1280 * 1280,
                                                    proj_b + l * 1280, h, h, 3072, 1280, 1280);
        ln_kernel<<<3072, 256, 0, stream>>>(h, ln2_w + l * 1280, ln2_b + l * 1280, xn);
        gemm_bf16<<<dim3(36, 24), 256, 0, stream>>>(xn, wt_gate + (size_t)l * 4608 * 1280,
                                                    gate_b + l * 4608, nullptr, gbuf, 3072, 4608, 1280);
        gemm_bf16<<<dim3(36, 24), 256, 0, stream>>>(xn, wt_up + (size_t)l * 4608 * 1280,
                                                    up_b + l * 4608, nullptr, ubuf, 3072, 4608, 1280);
        silu_mul_kernel<<<13824, 256, 0, stream>>>(gbuf, ubuf, mbuf);
        float* outp = (l == 3) ? (float*)d_out : h;
        gemm_bf16<<<dim3(10, 24), 256, 0, stream>>>(mbuf, wt_down + (size_t)l * 4608 * 1280,
                                                    down_b + l * 1280, h, outp, 3072, 1280, 4608);
    }
}

// Round 3
// 1753.856 us; speedup vs baseline: 1.5988x; 1.3101x over previous
//
#include <hip/hip_runtime.h>
#include <math.h>

typedef unsigned short u16;
typedef unsigned int u32;

using bf16x8 = __attribute__((ext_vector_type(8))) __bf16;
using f32x4  = __attribute__((ext_vector_type(4))) float;

#define SEQ 3072
#define HID 1280
#define NHEADS 16
#define HDIM 80
#define INTER 4608

#define LOG2E 1.44269504088896f
#define M2C   11.5415603f   /* 8 * log2(e) */

__device__ __forceinline__ u16 f2bf(float f) {
    union { float f; u32 u; } v; v.f = f;
    u32 u = v.u;
    u32 r = u + 0x7fffu + ((u >> 16) & 1u);   // round-to-nearest-even
    return (u16)(r >> 16);
}

__device__ __forceinline__ void gld16(const void* g, void* l) {
    __builtin_amdgcn_global_load_lds((const __attribute__((address_space(1))) void*)g,
                                     (__attribute__((address_space(3))) void*)l,
                                     16, 0, 0);
}

// swizzled fragment read: row-major tiles of 8 u16 chunks, chunk c at slot c^(row&7)
__device__ __forceinline__ bf16x8 frag8(const u16* base, int row, int ks, int quad) {
    int c = ks * 4 + quad;
    return *(const bf16x8*)&base[(row * 8 + (c ^ (row & 7))) * 8];
}

// ---------------- transpose + bf16 pack:  W (L,K,N) f32  ->  Wt (L,N,K) bf16
__global__ __launch_bounds__(256) void transpose_pack(const float* __restrict__ src,
                                                      u16* __restrict__ dst, int K, int N) {
    __shared__ float tile[32][33];
    int l = blockIdx.z;
    const float* s = src + (size_t)l * K * N;
    u16* d = dst + (size_t)l * N * K;
    int n0 = blockIdx.x * 32, k0 = blockIdx.y * 32;
    int tx = threadIdx.x & 31, ty = threadIdx.x >> 5;
#pragma unroll
    for (int i = 0; i < 4; i++) {
        int k = ty + i * 8;
        tile[k][tx] = s[(size_t)(k0 + k) * N + n0 + tx];
    }
    __syncthreads();
#pragma unroll
    for (int i = 0; i < 4; i++) {
        int n = ty + i * 8;
        d[(size_t)(n0 + n) * K + k0 + tx] = f2bf(tile[tx][n]);
    }
}

// ---------------- layernorm f32 -> bf16 (one row per block)
__global__ __launch_bounds__(256) void ln_kernel(const float* __restrict__ x,
                                                 const float* __restrict__ w,
                                                 const float* __restrict__ b,
                                                 u16* __restrict__ out) {
    int row = blockIdx.x;
    const float* xr = x + (size_t)row * HID;
    float v[5]; float s = 0.f, s2 = 0.f;
#pragma unroll
    for (int i = 0; i < 5; i++) { float t = xr[threadIdx.x + i * 256]; v[i] = t; s += t; s2 += t * t; }
#pragma unroll
    for (int off = 32; off > 0; off >>= 1) { s += __shfl_down(s, off); s2 += __shfl_down(s2, off); }
    __shared__ float red[8];
    int wv = threadIdx.x >> 6;
    if ((threadIdx.x & 63) == 0) { red[wv] = s; red[wv + 4] = s2; }
    __syncthreads();
    s  = red[0] + red[1] + red[2] + red[3];
    s2 = red[4] + red[5] + red[6] + red[7];
    float mu  = s * (1.f / HID);
    float var = s2 * (1.f / HID) - mu * mu;
    float rstd = rsqrtf(var + 1e-6f);
#pragma unroll
    for (int i = 0; i < 5; i++) {
        int col = threadIdx.x + i * 256;
        out[(size_t)row * HID + col] = f2bf((v[i] - mu) * rstd * w[col] + b[col]);
    }
}

// ---------------- qkv pack: fp32 qkv (S,3,16,80) -> rotary + bf16 attention layouts
__global__ __launch_bounds__(256) void qkv_pack(const float* __restrict__ qkv,
                                                const float* __restrict__ rot,
                                                u16* __restrict__ Qp, u16* __restrict__ Kp,
                                                u16* __restrict__ Vt) {
    const float QSC = 0.111803398874989485f * LOG2E;
    int s0 = blockIdx.x * 64, h = blockIdx.y;
    int tid = threadIdx.x;
    __shared__ u16 vlds[80 * 66];
    for (int idx = tid; idx < 64 * 40; idx += 256) {
        int r = idx / 40, d = idx - r * 40;
        const float* base = qkv + (size_t)(s0 + r) * 3840 + h * 80;
        float sn, cs;
        __sincosf(rot[(size_t)(s0 + r) * 40 + d], &sn, &cs);
        float q1 = base[d], q2 = base[d + 40];
        float k1 = base[1280 + d], k2 = base[1280 + d + 40];
        size_t ro = ((size_t)h * SEQ + s0 + r) * 128;
        Qp[ro + d]      = f2bf((q1 * cs - q2 * sn) * QSC);
        Qp[ro + d + 40] = f2bf((q2 * cs + q1 * sn) * QSC);
        Kp[ro + d]      = f2bf(k1 * cs - k2 * sn);
        Kp[ro + d + 40] = f2bf(k2 * cs + k1 * sn);
    }
    for (int idx = tid; idx < 64 * 48; idx += 256) {
        int r = idx / 48, d = 80 + (idx - r * 48);
        size_t ro = ((size_t)h * SEQ + s0 + r) * 128;
        Qp[ro + d] = 0; Kp[ro + d] = 0;
    }
    for (int idx = tid; idx < 64 * 80; idx += 256) {
        int r = idx / 80, d = idx - r * 80;
        vlds[d * 66 + r] = f2bf(qkv[(size_t)(s0 + r) * 3840 + 2560 + h * 80 + d]);
    }
    __syncthreads();
    for (int idx = tid; idx < 80 * 64; idx += 256) {
        int d = idx >> 6, ky = idx & 63;
        Vt[((size_t)h * 80 + d) * SEQ + s0 + ky] = vlds[d * 66 + ky];
    }
}

// ---------------- GEMM v3: BK=64, XCD-clustered block swizzle.
// MODE 0: 128x128 tile, f32 out + bias            (qkv)
// MODE 1: 128x64 tile,  f32 out + bias + residual (proj, down)
// MODE 2: 128x(64+64) dual gate/up, silu fuse, bf16 out (mlp)
template<int MODE>
__global__ __launch_bounds__(256) void gemm_v3(const u16* __restrict__ A,
                                               const u16* __restrict__ B0,
                                               const u16* __restrict__ B1,
                                               const float* __restrict__ bias0,
                                               const float* __restrict__ bias1,
                                               const float* __restrict__ res,
                                               float* __restrict__ outf,
                                               u16* __restrict__ outh,
                                               int N, int K, int sx, int sy) {
    __shared__ u16 As[8192];
    __shared__ u16 Bs[(MODE == 1) ? 4096 : 8192];
    int tid = threadIdx.x, lane = tid & 63, wave = tid >> 6;
    int quad = lane >> 4, r15 = lane & 15;
    int f = blockIdx.x, xcd = f & 7, j = f >> 3;
    int bx, by;
    if (sx) { bx = xcd * sx + j % sx; by = j / sx; }
    else    { by = xcd * sy + j % sy; bx = j / sy; }
    int mBase = by * 128;
    int nBase = (MODE == 0) ? bx * 128 : bx * 64;

    // staging descriptors: slot i*256+tid -> row 32i+(tid>>3), chunk (tid&7)^(row&7)
    int rs = tid >> 3, cs = tid & 7;
    int c0 = cs ^ (rs & 7);
    const u16* gA = A + (size_t)(mBase + rs) * K + c0 * 8;
    const u16* gB0 = B0 + (size_t)(nBase + rs) * K + c0 * 8;
    const u16* gB1 = (MODE == 2) ? (B1 + (size_t)(nBase + rs) * K + c0 * 8) : nullptr;
    u16* dA = &As[(wave * 64) * 8];

    f32x4 acc[MODE == 0 ? 4 : 2][4] = {};
    f32x4 acu[MODE == 2 ? 2 : 1][4] = {};

    int wm = wave >> 1, wn = wave & 1;   // MODE 0 quadrant
    int nK = K >> 6;
    for (int kt = 0; kt < nK; kt++) {
        const u16* a = gA + kt * 64;
        const u16* b0 = gB0 + kt * 64;
#pragma unroll
        for (int i = 0; i < 4; i++)
            gld16(a + (size_t)(i * 32) * K, dA + i * 2048);
        if constexpr (MODE == 0) {
#pragma unroll
            for (int i = 0; i < 4; i++)
                gld16(b0 + (size_t)(i * 32) * K, &Bs[(wave * 64) * 8 + i * 2048]);
        } else if constexpr (MODE == 1) {
#pragma unroll
            for (int i = 0; i < 2; i++)
                gld16(b0 + (size_t)(i * 32) * K, &Bs[(wave * 64) * 8 + i * 2048]);
        } else {
            const u16* b1 = gB1 + kt * 64;
#pragma unroll
            for (int i = 0; i < 2; i++)
                gld16(b0 + (size_t)(i * 32) * K, &Bs[(wave * 64) * 8 + i * 2048]);
#pragma unroll
            for (int i = 0; i < 2; i++)
                gld16(b1 + (size_t)(i * 32) * K, &Bs[4096 + (wave * 64) * 8 + i * 2048]);
        }
        __syncthreads();

#pragma unroll
        for (int ks = 0; ks < 2; ks++) {
            if constexpr (MODE == 0) {
                bf16x8 af[4], bf[4];
#pragma unroll
                for (int mi = 0; mi < 4; mi++) af[mi] = frag8(As, wm * 64 + mi * 16 + r15, ks, quad);
#pragma unroll
                for (int ni = 0; ni < 4; ni++) bf[ni] = frag8(Bs, wn * 64 + ni * 16 + r15, ks, quad);
#pragma unroll
                for (int mi = 0; mi < 4; mi++)
#pragma unroll
                    for (int ni = 0; ni < 4; ni++)
                        acc[mi][ni] = __builtin_amdgcn_mfma_f32_16x16x32_bf16(af[mi], bf[ni], acc[mi][ni], 0, 0, 0);
            } else if constexpr (MODE == 1) {
                bf16x8 af[2], bf[4];
#pragma unroll
                for (int mi = 0; mi < 2; mi++) af[mi] = frag8(As, wave * 32 + mi * 16 + r15, ks, quad);
#pragma unroll
                for (int ni = 0; ni < 4; ni++) bf[ni] = frag8(Bs, ni * 16 + r15, ks, quad);
#pragma unroll
                for (int mi = 0; mi < 2; mi++)
#pragma unroll
                    for (int ni = 0; ni < 4; ni++)
                        acc[mi][ni] = __builtin_amdgcn_mfma_f32_16x16x32_bf16(af[mi], bf[ni], acc[mi][ni], 0, 0, 0);
            } else {
                bf16x8 af[2];
#pragma unroll
                for (int mi = 0; mi < 2; mi++) af[mi] = frag8(As, wave * 32 + mi * 16 + r15, ks, quad);
#pragma unroll
                for (int ni = 0; ni < 4; ni++) {
                    bf16x8 bg = frag8(Bs, ni * 16 + r15, ks, quad);
                    bf16x8 bu = frag8(Bs + 4096, ni * 16 + r15, ks, quad);
#pragma unroll
                    for (int mi = 0; mi < 2; mi++) {
                        acc[mi][ni] = __builtin_amdgcn_mfma_f32_16x16x32_bf16(af[mi], bg, acc[mi][ni], 0, 0, 0);
                        acu[mi][ni] = __builtin_amdgcn_mfma_f32_16x16x32_bf16(af[mi], bu, acu[mi][ni], 0, 0, 0);
                    }
                }
            }
        }
        __syncthreads();
    }

    if constexpr (MODE == 0) {
#pragma unroll
        for (int ni = 0; ni < 4; ni++) {
            int col = nBase + wn * 64 + ni * 16 + r15;
            float bv = bias0[col];
#pragma unroll
            for (int mi = 0; mi < 4; mi++)
#pragma unroll
                for (int jj = 0; jj < 4; jj++) {
                    int row = mBase + wm * 64 + mi * 16 + quad * 4 + jj;
                    outf[(size_t)row * N + col] = acc[mi][ni][jj] + bv;
                }
        }
    } else if constexpr (MODE == 1) {
#pragma unroll
        for (int ni = 0; ni < 4; ni++) {
            int col = nBase + ni * 16 + r15;
            float bv = bias0[col];
#pragma unroll
            for (int mi = 0; mi < 2; mi++)
#pragma unroll
                for (int jj = 0; jj < 4; jj++) {
                    int row = mBase + wave * 32 + mi * 16 + quad * 4 + jj;
                    outf[(size_t)row * N + col] = acc[mi][ni][jj] + bv + res[(size_t)row * N + col];
                }
        }
    } else {
#pragma unroll
        for (int ni = 0; ni < 4; ni++) {
            int col = nBase + ni * 16 + r15;
            float gb = bias0[col], ub = bias1[col];
#pragma unroll
            for (int mi = 0; mi < 2; mi++)
#pragma unroll
                for (int jj = 0; jj < 4; jj++) {
                    int row = mBase + wave * 32 + mi * 16 + quad * 4 + jj;
                    float g = acc[mi][ni][jj] + gb;
                    float u = acu[mi][ni][jj] + ub;
                    float sg = g / (1.f + __expf(-g));
                    outh[(size_t)row * INTER + col] = f2bf(sg * u);
                }
        }
    }
}

// ---------------- flash attention with sinks v2 (unchanged from round 2)
__global__ __launch_bounds__(256) void attn_kernel(const u16* __restrict__ Qp,
                                                   const u16* __restrict__ Kp,
                                                   const u16* __restrict__ Vt,
                                                   const float* __restrict__ s_aux,
                                                   u16* __restrict__ out, int windowed) {
    __shared__ u16 q_lds[8192];
    __shared__ u16 k_lds[8192];
    __shared__ u16 v_lds[5120];
    __shared__ u16 p_lds[64 * 72];

    int qt = blockIdx.x, h = blockIdx.y;
    int tid = threadIdx.x, lane = tid & 63, wave = tid >> 6;
    int quad = lane >> 4, r15 = lane & 15;

    const u16* Qh = Qp + (size_t)h * SEQ * 128;
    const u16* Kh = Kp + (size_t)h * SEQ * 128;
    const u16* Vh = Vt + (size_t)h * 80 * SEQ;

    {
        int q0 = qt * 64;
#pragma unroll
        for (int i = 0; i < 4; i++) {
            int slot = i * 256 + wave * 64 + lane;
            int row = slot >> 4, cc = slot & 15;
            int c = cc ^ (row & 7);
            gld16(Qh + (size_t)(q0 + row) * 128 + c * 8, &q_lds[(i * 256 + wave * 64) * 8]);
        }
    }
    __syncthreads();
    bf16x8 aq[3];
#pragma unroll
    for (int ks = 0; ks < 3; ks++) {
        int row = wave * 16 + r15;
        int c = ks * 4 + quad;
        aq[ks] = *(const bf16x8*)&q_lds[(row * 16 + (c ^ (row & 7))) * 8];
    }

    float l_j[4] = {0.f, 0.f, 0.f, 0.f};
    f32x4 ov[5] = {};

    int nT = windowed ? 1 : (SEQ / 64);
    int tBase = windowed ? qt : 0;
    for (int t = 0; t < nT; t++) {
        int key0 = (tBase + t) * 64;
        __syncthreads();
#pragma unroll
        for (int i = 0; i < 4; i++) {
            int slot = i * 256 + wave * 64 + lane;
            int row = slot >> 4, cc = slot & 15;
            int c = cc ^ (row & 7);
            gld16(Kh + (size_t)(key0 + row) * 128 + c * 8, &k_lds[(i * 256 + wave * 64) * 8]);
        }
#pragma unroll
        for (int i = 0; i < 2; i++) {
            int slot = i * 256 + wave * 64 + lane;
            int row = slot >> 3, cc = slot & 7;
            int c = cc ^ (row & 7);
            gld16(Vh + (size_t)row * SEQ + key0 + c * 8, &v_lds[(i * 256 + wave * 64) * 8]);
        }
        if (wave < 2) {
            int slot = 512 + wave * 64 + lane;
            int row = slot >> 3, cc = slot & 7;
            int c = cc ^ (row & 7);
            gld16(Vh + (size_t)row * SEQ + key0 + c * 8, &v_lds[(512 + wave * 64) * 8]);
        }
        __syncthreads();

        f32x4 sc[4];
#pragma unroll
        for (int nt = 0; nt < 4; nt++) {
            f32x4 z = {};
#pragma unroll
            for (int ks = 0; ks < 3; ks++) {
                int row = nt * 16 + r15;
                int c = ks * 4 + quad;
                bf16x8 bk = *(const bf16x8*)&k_lds[(row * 16 + (c ^ (row & 7))) * 8];
                z = __builtin_amdgcn_mfma_f32_16x16x32_bf16(aq[ks], bk, z, 0, 0, 0);
            }
            sc[nt] = z;
        }
#pragma unroll
        for (int nt = 0; nt < 4; nt++)
#pragma unroll
            for (int jj = 0; jj < 4; jj++) {
                float p = __builtin_amdgcn_exp2f(sc[nt][jj] - M2C);
                l_j[jj] += p;
                p_lds[(wave * 16 + quad * 4 + jj) * 72 + nt * 16 + r15] = f2bf(p);
            }
        asm volatile("s_waitcnt lgkmcnt(0)" ::: "memory");
        bf16x8 ap[2];
#pragma unroll
        for (int ks = 0; ks < 2; ks++)
            ap[ks] = *(const bf16x8*)&p_lds[(wave * 16 + r15) * 72 + ks * 32 + quad * 8];
#pragma unroll
        for (int t5 = 0; t5 < 5; t5++)
#pragma unroll
            for (int ks = 0; ks < 2; ks++) {
                int d = t5 * 16 + r15;
                int c = ks * 4 + quad;
                bf16x8 bv = *(const bf16x8*)&v_lds[(d * 8 + (c ^ (d & 7))) * 8];
                ov[t5] = __builtin_amdgcn_mfma_f32_16x16x32_bf16(ap[ks], bv, ov[t5], 0, 0, 0);
            }
    }
#pragma unroll
    for (int off = 1; off < 16; off <<= 1)
#pragma unroll
        for (int jj = 0; jj < 4; jj++)
            l_j[jj] += __shfl_xor(l_j[jj], off, 64);
    float sink = s_aux[h];
    float se = __builtin_amdgcn_exp2f(sink * LOG2E - M2C);
#pragma unroll
    for (int jj = 0; jj < 4; jj++) l_j[jj] = 1.f / (l_j[jj] + se);
#pragma unroll
    for (int t5 = 0; t5 < 5; t5++)
#pragma unroll
        for (int jj = 0; jj < 4; jj++) {
            int row = qt * 64 + wave * 16 + quad * 4 + jj;
            int d = t5 * 16 + r15;
            out[(size_t)row * HID + h * 80 + d] = f2bf(ov[t5][jj] * l_j[jj]);
        }
}

__global__ __launch_bounds__(256) void copy4_kernel(const float4* __restrict__ src,
                                                    float4* __restrict__ dst) {
    size_t i = (size_t)blockIdx.x * 256 + threadIdx.x;
    dst[i] = src[i];
}

extern "C" void kernel_launch(void* const* d_in, const int* in_sizes, int n_in,
                              void* d_out, int out_size, void* d_ws, size_t ws_size,
                              hipStream_t stream) {
    const float* x      = (const float*)d_in[0];
    const float* rot    = (const float*)d_in[1];
    const float* s_aux  = (const float*)d_in[2];
    const float* ln1_w  = (const float*)d_in[3];
    const float* ln1_b  = (const float*)d_in[4];
    const float* qkv_w  = (const float*)d_in[5];
    const float* qkv_b  = (const float*)d_in[6];
    const float* proj_w = (const float*)d_in[7];
    const float* proj_b = (const float*)d_in[8];
    const float* ln2_w  = (const float*)d_in[9];
    const float* ln2_b  = (const float*)d_in[10];
    const float* gate_w = (const float*)d_in[11];
    const float* gate_b = (const float*)d_in[12];
    const float* up_w   = (const float*)d_in[13];
    const float* up_b   = (const float*)d_in[14];
    const float* down_w = (const float*)d_in[15];
    const float* down_b = (const float*)d_in[16];

    char* ws = (char*)d_ws;
    size_t off = 0;
    auto alloc = [&](size_t n) -> char* {
        char* p = ws + off; off += (n + 255) & ~(size_t)255; return p;
    };
    u16* wt_qkv  = (u16*)alloc((size_t)4 * 3840 * 1280 * 2);
    u16* wt_proj = (u16*)alloc((size_t)4 * 1280 * 1280 * 2);
    u16* wt_gate = (u16*)alloc((size_t)4 * 4608 * 1280 * 2);
    u16* wt_up   = (u16*)alloc((size_t)4 * 4608 * 1280 * 2);
    u16* wt_down = (u16*)alloc((size_t)4 * 1280 * 4608 * 2);
    float* h     = (float*)alloc((size_t)3072 * 1280 * 4);
    u16*  xn     = (u16*)alloc((size_t)3072 * 1280 * 2);
    float* gbuf  = (float*)alloc((size_t)3072 * 4608 * 4);
    float* qkvb  = gbuf;  // alias: qkv buffer dead before MLP
    u16*  attnb  = (u16*)alloc((size_t)3072 * 1280 * 2);
    float* ubuf  = (float*)alloc((size_t)3072 * 4608 * 4);
    u16*  mbuf   = (u16*)alloc((size_t)3072 * 4608 * 2);
    u16* Qp  = (u16*)ubuf;
    u16* Kp  = Qp + (size_t)NHEADS * SEQ * 128;
    u16* Vtp = Kp + (size_t)NHEADS * SEQ * 128;

    transpose_pack<<<dim3(120, 40, 4), 256, 0, stream>>>(qkv_w,  wt_qkv,  1280, 3840);
    transpose_pack<<<dim3(40,  40, 4), 256, 0, stream>>>(proj_w, wt_proj, 1280, 1280);
    transpose_pack<<<dim3(144, 40, 4), 256, 0, stream>>>(gate_w, wt_gate, 1280, 4608);
    transpose_pack<<<dim3(144, 40, 4), 256, 0, stream>>>(up_w,   wt_up,   1280, 4608);
    transpose_pack<<<dim3(40, 144, 4), 256, 0, stream>>>(down_w, wt_down, 4608, 1280);

    copy4_kernel<<<3840, 256, 0, stream>>>((const float4*)x, (float4*)h);

    for (int l = 0; l < 4; l++) {
        ln_kernel<<<3072, 256, 0, stream>>>(h, ln1_w + l * 1280, ln1_b + l * 1280, xn);
        gemm_v3<0><<<720, 256, 0, stream>>>(xn, wt_qkv + (size_t)l * 3840 * 1280, nullptr,
                                            qkv_b + l * 3840, nullptr, nullptr, qkvb, nullptr,
                                            3840, 1280, 0, 3);
        qkv_pack<<<dim3(48, 16), 256, 0, stream>>>(qkvb, rot, Qp, Kp, Vtp);
        attn_kernel<<<dim3(48, 16), 256, 0, stream>>>(Qp, Kp, Vtp, s_aux, attnb, (l == 3) ? 0 : 1);
        gemm_v3<1><<<480, 256, 0, stream>>>(attnb, wt_proj + (size_t)l * 1280 * 1280, nullptr,
                                            proj_b + l * 1280, nullptr, h, h, nullptr,
                                            1280, 1280, 0, 3);
        ln_kernel<<<3072, 256, 0, stream>>>(h, ln2_w + l * 1280, ln2_b + l * 1280, xn);
        gemm_v3<2><<<1728, 256, 0, stream>>>(xn, wt_gate + (size_t)l * 4608 * 1280,
                                             wt_up + (size_t)l * 4608 * 1280,
                                             gate_b + l * 4608, up_b + l * 4608, nullptr,
                                             nullptr, mbuf, 4608, 1280, 9, 0);
        float* outp = (l == 3) ? (float*)d_out : h;
        gemm_v3<1><<<480, 256, 0, stream>>>(mbuf, wt_down + (size_t)l * 4608 * 1280, nullptr,
                                            down_b + l * 1280, nullptr, h, outp, nullptr,
                                            1280, 4608, 0, 3);
    }
}